// Round 6
// baseline (1288.241 us; speedup 1.0000x reference)
//
#include <hip/hip_runtime.h>
#include <hip/hip_bf16.h>
#include <stddef.h>

#define NN    8
#define CIN   256
#define TT    128
#define VV    128
#define OUTC  512
#define HH    8
#define DD    64

typedef _Float16 f16;
typedef _Float16 f16x8 __attribute__((ext_vector_type(8)));
typedef float    f32x4 __attribute__((ext_vector_type(4)));

#define MFMA16(a, b, c) __builtin_amdgcn_mfma_f32_16x16x32_f16((a), (b), (c), 0, 0, 0)

// ---- workspace layout (bytes) ----
// All intermediate buffers are stored in MFMA-FRAGMENT-LINEAR order:
//   element (row o, col c) of an R x NC f16 matrix lives at f16-offset
//     (o>>4)*(NC*16) + (c>>5)*512 + ((c>>3)&3)*128 + (o&15)*8 + (c&7)
//   so one wave64 fragment load (16 rows x 32 cols, lane l, 16B/lane) reads
//   a CONTIGUOUS 1KB block: base + instr*1024 + l*16.
#define XE_OFF   ((size_t)0)
#define WQ_OFF   ((size_t)67108864)
#define WK_OFF   ((size_t)67371008)
#define WV_OFF   ((size_t)67633152)
#define WP_OFF   ((size_t)67895296)
#define OE_OFF   ((size_t)68419584)

// fragment-linear f16 offset for an NC-column matrix
__device__ __forceinline__ size_t fragoff(int o, int c, int nc)
{
    return (size_t)(o >> 4) * (nc * 16) + ((c >> 5) << 9) + (((c >> 3) & 3) << 7)
         + ((o & 15) << 3) + (c & 7);
}

// -------------------------------------------------------------------------
// Kernel A: blocks 0..1023 transpose+convert x (n,c,t,v) fp32 -> xe f16
// (fragment-linear per (n,t), NC=256). blocks 1024..1039 convert weights
// fp32 -> f16 fragment-linear (wq scaled by 8 = sqrt(D)).
// -------------------------------------------------------------------------
__global__ __launch_bounds__(256, 4)
void prep_kernel(const float* __restrict__ x,
                 const float* __restrict__ wq,
                 const float* __restrict__ wk,
                 const float* __restrict__ wv,
                 const float* __restrict__ wp,
                 f16* __restrict__ xe,
                 f16* __restrict__ wq16, f16* __restrict__ wk16,
                 f16* __restrict__ wv16, f16* __restrict__ wp16)
{
    const int bid = blockIdx.x;
    const int tid = threadIdx.x;

    if (bid < NN * TT) {
        __shared__ f16 tile[128 * 136];   // (c_local, v), stride 136
        const int n = bid >> 7;
        const int t = bid & 127;

        for (int p = 0; p < 2; ++p) {
            #pragma unroll
            for (int it = 0; it < 4; ++it) {
                const int cl = it * 32 + (tid >> 3);        // 0..127
                const int c  = p * 128 + cl;
                const int v0 = (tid & 7) * 16;
                const float* src = x + (((size_t)(n * CIN + c) * TT + t) * VV) + v0;
                #pragma unroll
                for (int q = 0; q < 4; ++q) {
                    const float4 xv = *(const float4*)(src + q * 4);
                    union { uint2 u; f16 h[4]; } pk;
                    pk.h[0] = (f16)xv.x; pk.h[1] = (f16)xv.y;
                    pk.h[2] = (f16)xv.z; pk.h[3] = (f16)xv.w;
                    *(uint2*)&tile[cl * 136 + v0 + q * 4] = pk.u;
                }
            }
            __syncthreads();
            {
                const int v  = tid >> 1;
                const int ch = tid & 1;
                f16* dstbase = xe + (size_t)(n * TT + t) * VV * 256;
                #pragma unroll
                for (int q8 = 0; q8 < 8; ++q8) {
                    const int c0 = p * 128 + ch * 64 + q8 * 8;
                    union { int4 u; f16 h[8]; } pk;
                    #pragma unroll
                    for (int s = 0; s < 8; ++s)
                        pk.h[s] = tile[(ch * 64 + q8 * 8 + s) * 136 + v];
                    *(int4*)(dstbase + fragoff(v, c0, 256)) = pk.u;
                }
            }
            __syncthreads();
        }
    } else {
        const int gid = (bid - NN * TT) * 256 + tid;   // 0..4095
        for (int i = gid; i < 163840; i += 4096) {
            const int e = i * 4;
            union { uint2 u; f16 h[4]; } pk;
            if (e < 131072) {
                const float4 v = *(const float4*)(wq + e);
                pk.h[0] = (f16)(v.x * 8.0f); pk.h[1] = (f16)(v.y * 8.0f);
                pk.h[2] = (f16)(v.z * 8.0f); pk.h[3] = (f16)(v.w * 8.0f);
                *(uint2*)(wq16 + fragoff(e >> 8, e & 255, 256)) = pk.u;
            } else if (e < 262144) {
                const int e2 = e - 131072;
                const float4 v = *(const float4*)(wk + e2);
                pk.h[0] = (f16)v.x; pk.h[1] = (f16)v.y; pk.h[2] = (f16)v.z; pk.h[3] = (f16)v.w;
                *(uint2*)(wk16 + fragoff(e2 >> 8, e2 & 255, 256)) = pk.u;
            } else if (e < 393216) {
                const int e2 = e - 262144;
                const float4 v = *(const float4*)(wv + e2);
                pk.h[0] = (f16)v.x; pk.h[1] = (f16)v.y; pk.h[2] = (f16)v.z; pk.h[3] = (f16)v.w;
                *(uint2*)(wv16 + fragoff(e2 >> 8, e2 & 255, 256)) = pk.u;
            } else {
                const int e2 = e - 393216;
                const float4 v = *(const float4*)(wp + e2);
                pk.h[0] = (f16)v.x; pk.h[1] = (f16)v.y; pk.h[2] = (f16)v.z; pk.h[3] = (f16)v.w;
                *(uint2*)(wp16 + fragoff(e2 >> 9, e2 & 511, 512)) = pk.u;
            }
        }
    }
}

// -------------------------------------------------------------------------
// In-register fragment regroup: MFMA C-layout (rows on g*4+i, col on r) for a
// 32-row x 16-col chunk -> A/B fragment layout (col on r, rows 8/lane on g).
// -------------------------------------------------------------------------
__device__ __forceinline__ f16x8 regroup32(f32x4 T0, f32x4 T1, int g, int r)
{
    union { unsigned u; f16 h[2]; } pa, pb, pc, pd;
    pa.h[0] = (f16)T0[0]; pa.h[1] = (f16)T0[1];
    pb.h[0] = (f16)T0[2]; pb.h[1] = (f16)T0[3];
    pc.h[0] = (f16)T1[0]; pc.h[1] = (f16)T1[1];
    pd.h[0] = (f16)T1[2]; pd.h[1] = (f16)T1[3];
    const int s0 = r + ((g & 1) << 5);
    const int s1 = s0 + 16;
    const bool lo = (g < 2);
    const unsigned a0 = (unsigned)__shfl((int)pa.u, s0, 64);
    const unsigned c0 = (unsigned)__shfl((int)pc.u, s0, 64);
    const unsigned b0 = (unsigned)__shfl((int)pb.u, s0, 64);
    const unsigned d0 = (unsigned)__shfl((int)pd.u, s0, 64);
    const unsigned a1 = (unsigned)__shfl((int)pa.u, s1, 64);
    const unsigned c1 = (unsigned)__shfl((int)pc.u, s1, 64);
    const unsigned b1 = (unsigned)__shfl((int)pb.u, s1, 64);
    const unsigned d1 = (unsigned)__shfl((int)pd.u, s1, 64);
    union { unsigned u[4]; f16x8 v; } out;
    out.u[0] = lo ? a0 : c0;
    out.u[1] = lo ? b0 : d0;
    out.u[2] = lo ? a1 : c1;
    out.u[3] = lo ? b1 : d1;
    return out.v;
}

// -------------------------------------------------------------------------
// Kernel B: one block per (n,t,h), XCD-chunked swizzle, fragment-linear
// operand loads. MERGED q/k/v projection (one pass, 14 loads : 24 MFMA per
// K-step; measured 104 VGPR in R1 -> fits the (256,4) cap of 128).
// Q in registers; K,V in LDS; ONE barrier. setprio around MFMA clusters
// (4 independent blocks/CU at staggered phases = the regime where it pays).
// -------------------------------------------------------------------------
__global__ __launch_bounds__(256, 4)
void qkv_attn_kernel(const f16* __restrict__ xe,
                     const f16* __restrict__ wq16,
                     const f16* __restrict__ wk16,
                     const f16* __restrict__ wv16,
                     f16* __restrict__ oe)
{
    // sK: (v,128 x 72) | sVT: (d,64 x 136)
    __shared__ f16 smem[17920];
    f16* sK  = smem;              // 9216 halves
    f16* sVT = smem + 9216;       // 8704 halves

    const int tid = threadIdx.x;
    const int wid = tid >> 6;
    const int l   = tid & 63;
    const int r   = l & 15;
    const int g   = l >> 4;

    // XCD-chunked decode (grid 8192 = 8 XCD x 1024, bijective).
    const int i   = blockIdx.x;
    const int xcd = i & 7;
    const int m   = i >> 3;                 // 0..1023
    const int nt  = xcd * 128 + (m >> 3);   // 0..1023
    const int h   = m & 7;
    const int n   = nt >> 7;
    const int t   = nt & 127;

    const f16* xrow = xe + (size_t)(n * TT + t) * VV * 256;   // fragment-linear

    // ---------------- Phase 1: merged q,k,v projection ----------------
    f32x4 accq[4][2], acck[4][2], accv[4][2];
    #pragma unroll
    for (int dt = 0; dt < 4; ++dt)
        #pragma unroll
        for (int vt = 0; vt < 2; ++vt) {
            accq[dt][vt] = (f32x4)0.0f;
            acck[dt][vt] = (f32x4)0.0f;
            accv[dt][vt] = (f32x4)0.0f;
        }

    for (int ks = 0; ks < 8; ++ks) {
        f16x8 aq[4], ak[4], av[4], bx[2];
        #pragma unroll
        for (int dt = 0; dt < 4; ++dt) {
            aq[dt] = *(const f16x8*)(wq16 + (size_t)(h * 4 + dt) * 4096 + ks * 512 + l * 8);
            ak[dt] = *(const f16x8*)(wk16 + (size_t)(h * 4 + dt) * 4096 + ks * 512 + l * 8);
            av[dt] = *(const f16x8*)(wv16 + (size_t)(h * 4 + dt) * 4096 + ks * 512 + l * 8);
        }
        #pragma unroll
        for (int vt = 0; vt < 2; ++vt)
            bx[vt] = *(const f16x8*)(xrow + (size_t)(wid * 2 + vt) * 4096 + ks * 512 + l * 8);
        __builtin_amdgcn_s_setprio(1);
        #pragma unroll
        for (int dt = 0; dt < 4; ++dt)
            #pragma unroll
            for (int vt = 0; vt < 2; ++vt) {
                accq[dt][vt] = MFMA16(aq[dt], bx[vt], accq[dt][vt]);
                acck[dt][vt] = MFMA16(ak[dt], bx[vt], acck[dt][vt]);
                accv[dt][vt] = MFMA16(av[dt], bx[vt], accv[dt][vt]);
            }
        __builtin_amdgcn_s_setprio(0);
    }

    // write K transposed to (v, d) — packed b64
    #pragma unroll
    for (int dt = 0; dt < 4; ++dt)
        #pragma unroll
        for (int vt = 0; vt < 2; ++vt) {
            const int v = wid * 32 + vt * 16 + r;
            union { uint2 u; f16 h4[4]; } pk;
            #pragma unroll
            for (int i2 = 0; i2 < 4; ++i2)
                pk.h4[i2] = (f16)acck[dt][vt][i2];
            *(uint2*)&sK[v * 72 + dt * 16 + g * 4] = pk.u;
        }
    // write V^T (d, w) — column scatter b16
    #pragma unroll
    for (int dt = 0; dt < 4; ++dt)
        #pragma unroll
        for (int wt = 0; wt < 2; ++wt) {
            const int w = wid * 32 + wt * 16 + r;
            #pragma unroll
            for (int i2 = 0; i2 < 4; ++i2)
                sVT[(dt * 16 + g * 4 + i2) * 136 + w] = (f16)accv[dt][wt][i2];
        }
    // Q stays in registers: regroup acc layout -> B-frag layout (wave-local v)
    f16x8 qfrag[2][2];   // [vt][ks]: Q[v=wid*32+vt*16+r][d=ks*32+g*8 ..+7]
    #pragma unroll
    for (int vt = 0; vt < 2; ++vt) {
        qfrag[vt][0] = regroup32(accq[0][vt], accq[1][vt], g, r);
        qfrag[vt][1] = regroup32(accq[2][vt], accq[3][vt], g, r);
    }
    __syncthreads();   // the ONLY barrier: sK/sVT complete before reads

    // ---------------- Phase 2: S^T = K Q^T (w x v), scale folded in wq ----
    f32x4 sT[8][2];
    #pragma unroll
    for (int mt = 0; mt < 8; ++mt)
        #pragma unroll
        for (int vt = 0; vt < 2; ++vt) sT[mt][vt] = (f32x4)0.0f;

    #pragma unroll
    for (int ks = 0; ks < 2; ++ks) {
        const int ko = ks * 32 + g * 8;
        #pragma unroll
        for (int mt = 0; mt < 8; ++mt) {
            const f16x8 a = *(const f16x8*)&sK[(mt * 16 + r) * 72 + ko];
            __builtin_amdgcn_s_setprio(1);
            #pragma unroll
            for (int vt = 0; vt < 2; ++vt)
                sT[mt][vt] = MFMA16(a, qfrag[vt][ks], sT[mt][vt]);
            __builtin_amdgcn_s_setprio(0);
        }
    }

    // ---------------- Phase 3: softmax over w (in-register) ----------------
    float inv[2];
    #pragma unroll
    for (int vt = 0; vt < 2; ++vt) {
        float mx = -3.0e38f;
        #pragma unroll
        for (int mt = 0; mt < 8; ++mt)
            #pragma unroll
            for (int i2 = 0; i2 < 4; ++i2) mx = fmaxf(mx, sT[mt][vt][i2]);
        mx = fmaxf(mx, __shfl_xor(mx, 16));
        mx = fmaxf(mx, __shfl_xor(mx, 32));
        float sm = 0.0f;
        #pragma unroll
        for (int mt = 0; mt < 8; ++mt)
            #pragma unroll
            for (int i2 = 0; i2 < 4; ++i2) {
                const float e = __expf(sT[mt][vt][i2] - mx);
                sT[mt][vt][i2] = e;
                sm += e;
            }
        sm += __shfl_xor(sm, 16);
        sm += __shfl_xor(sm, 32);
        inv[vt] = 1.0f / sm;
    }

    // ---------------- Phase 4: o^T = V^T P^T (d x v), P regrouped in-reg ----
    f32x4 oT[4][2];
    #pragma unroll
    for (int dt = 0; dt < 4; ++dt)
        #pragma unroll
        for (int vt = 0; vt < 2; ++vt) oT[dt][vt] = (f32x4)0.0f;

    #pragma unroll
    for (int ks = 0; ks < 4; ++ks) {
        const int ko = ks * 32 + g * 8;
        f16x8 pf[2];
        #pragma unroll
        for (int vt = 0; vt < 2; ++vt)
            pf[vt] = regroup32(sT[2 * ks][vt], sT[2 * ks + 1][vt], g, r);
        #pragma unroll
        for (int dt = 0; dt < 4; ++dt) {
            const f16x8 a = *(const f16x8*)&sVT[(dt * 16 + r) * 136 + ko];
            __builtin_amdgcn_s_setprio(1);
            #pragma unroll
            for (int vt = 0; vt < 2; ++vt)
                oT[dt][vt] = MFMA16(a, pf[vt], oT[dt][vt]);
            __builtin_amdgcn_s_setprio(0);
        }
    }

    // epilogue: normalize, store fragment-linear oe (NC=512).
    f16* oerow = oe + (size_t)(n * TT + t) * VV * 512;
    #pragma unroll
    for (int dt = 0; dt < 4; ++dt)
        #pragma unroll
        for (int vt = 0; vt < 2; ++vt) {
            union { uint2 u; f16 h4[4]; } pk;
            #pragma unroll
            for (int i2 = 0; i2 < 4; ++i2) pk.h4[i2] = (f16)(oT[dt][vt][i2] * inv[vt]);
            f16* dst = oerow + (size_t)(wid * 2 + vt) * 8192
                     + (h * 2 + (dt >> 1)) * 512
                     + ((dt & 1) * 2 + (g >> 1)) * 128
                     + r * 8 + (g & 1) * 4;
            *(uint2*)dst = pk.u;
        }
}

// -------------------------------------------------------------------------
// Kernel C: out[n,o,t,v] = wp @ o + bp. One block per (n, t, og): 256 o-rows
// x full 128 v. acc[4][8] -> 32 MFMA : 12 loads per K-step (ratio 2.67).
// No LDS; fragment-linear loads; stores are full 512B-contiguous (o,t) rows.
// XCD-chunked swizzle: both og-blocks of one (n,t) consecutive per XCD.
// -------------------------------------------------------------------------
__global__ __launch_bounds__(256, 2)
void out_proj_kernel(const f16* __restrict__ oe,
                     const f16* __restrict__ wp16,
                     const float* __restrict__ bp,
                     float* __restrict__ out)
{
    const int tid = threadIdx.x;
    const int wid = tid >> 6;
    const int l   = tid & 63;
    const int r   = l & 15;
    const int g   = l >> 4;

    // grid = 2048 = 8 XCDs x 256.
    const int i   = blockIdx.x;
    const int xcd = i & 7;
    const int m   = i >> 3;                 // 0..255
    const int nt  = xcd * 128 + (m >> 1);   // 0..1023
    const int og  = m & 1;
    const int n   = nt >> 7;
    const int t   = nt & 127;

    const f16* brow = oe + (size_t)(n * TT + t) * VV * 512;   // fragment-linear

    f32x4 acc[4][8];
    #pragma unroll
    for (int mi = 0; mi < 4; ++mi)
        #pragma unroll
        for (int nt2 = 0; nt2 < 8; ++nt2) acc[mi][nt2] = (f32x4)0.0f;

    for (int ks = 0; ks < 16; ++ks) {
        f16x8 a[4], b[8];
        #pragma unroll
        for (int mi = 0; mi < 4; ++mi)
            a[mi] = *(const f16x8*)(wp16 + (size_t)(og * 16 + wid * 4 + mi) * 8192 + ks * 512 + l * 8);
        #pragma unroll
        for (int nt2 = 0; nt2 < 8; ++nt2)
            b[nt2] = *(const f16x8*)(brow + (size_t)nt2 * 8192 + ks * 512 + l * 8);
        __builtin_amdgcn_s_setprio(1);
        #pragma unroll
        for (int mi = 0; mi < 4; ++mi)
            #pragma unroll
            for (int nt2 = 0; nt2 < 8; ++nt2)
                acc[mi][nt2] = MFMA16(a[mi], b[nt2], acc[mi][nt2]);
        __builtin_amdgcn_s_setprio(0);
    }

    #pragma unroll
    for (int mi = 0; mi < 4; ++mi) {
        const int obase = og * 256 + (wid * 4 + mi) * 16 + g * 4;
        const float b0 = bp[obase + 0];
        const float b1 = bp[obase + 1];
        const float b2 = bp[obase + 2];
        const float b3 = bp[obase + 3];
        #pragma unroll
        for (int nt2 = 0; nt2 < 8; ++nt2) {
            const int v = nt2 * 16 + r;
            float* dst = out + ((size_t)(n * OUTC + obase) * TT + t) * VV + v;
            dst[0 * TT * VV] = acc[mi][nt2][0] + b0;
            dst[1 * TT * VV] = acc[mi][nt2][1] + b1;
            dst[2 * TT * VV] = acc[mi][nt2][2] + b2;
            dst[3 * TT * VV] = acc[mi][nt2][3] + b3;
        }
    }
}

extern "C" void kernel_launch(void* const* d_in, const int* in_sizes, int n_in,
                              void* d_out, int out_size, void* d_ws, size_t ws_size,
                              hipStream_t stream)
{
    const float* x  = (const float*)d_in[0];
    const float* wq = (const float*)d_in[1];
    const float* wk = (const float*)d_in[2];
    const float* wv = (const float*)d_in[3];
    const float* wp = (const float*)d_in[4];
    const float* bp = (const float*)d_in[5];
    float* out = (float*)d_out;

    char* ws = (char*)d_ws;
    f16* xe   = (f16*)(ws + XE_OFF);
    f16* wq16 = (f16*)(ws + WQ_OFF);
    f16* wk16 = (f16*)(ws + WK_OFF);
    f16* wv16 = (f16*)(ws + WV_OFF);
    f16* wp16 = (f16*)(ws + WP_OFF);
    f16* oe   = (f16*)(ws + OE_OFF);

    prep_kernel<<<NN * TT + 16, 256, 0, stream>>>(x, wq, wk, wv, wp, xe, wq16, wk16, wv16, wp16);
    qkv_attn_kernel<<<NN * TT * HH, 256, 0, stream>>>(xe, wq16, wk16, wv16, oe);
    out_proj_kernel<<<NN * TT * 2, 256, 0, stream>>>(oe, wp16, bp, out);
}

// Round 7
// 678.136 us; speedup vs baseline: 1.8997x; 1.8997x over previous
//
#include <hip/hip_runtime.h>
#include <hip/hip_bf16.h>
#include <stddef.h>

#define NN    8
#define CIN   256
#define TT    128
#define VV    128
#define OUTC  512
#define HH    8
#define DD    64

typedef _Float16 f16;
typedef _Float16 f16x8 __attribute__((ext_vector_type(8)));
typedef float    f32x4 __attribute__((ext_vector_type(4)));

#define MFMA16(a, b, c) __builtin_amdgcn_mfma_f32_16x16x32_f16((a), (b), (c), 0, 0, 0)

// ---- workspace layout (bytes) ----
// All intermediate buffers are stored in MFMA-FRAGMENT-LINEAR order:
//   element (row o, col c) of an R x NC f16 matrix lives at f16-offset
//     (o>>4)*(NC*16) + (c>>5)*512 + ((c>>3)&3)*128 + (o&15)*8 + (c&7)
//   so one wave64 fragment load (16 rows x 32 cols, lane l, 16B/lane) reads
//   a CONTIGUOUS 1KB block: base + instr*1024 + l*16.
#define XE_OFF   ((size_t)0)
#define WQ_OFF   ((size_t)67108864)
#define WK_OFF   ((size_t)67371008)
#define WV_OFF   ((size_t)67633152)
#define WP_OFF   ((size_t)67895296)
#define OE_OFF   ((size_t)68419584)

// fragment-linear f16 offset for an NC-column matrix
__device__ __forceinline__ size_t fragoff(int o, int c, int nc)
{
    return (size_t)(o >> 4) * (nc * 16) + ((c >> 5) << 9) + (((c >> 3) & 3) << 7)
         + ((o & 15) << 3) + (c & 7);
}

// -------------------------------------------------------------------------
// Kernel A: blocks 0..1023: LDS-free transpose+convert x (n,c,t,v) fp32 ->
// xe f16 fragment-linear. Lane loads float2 (2 consecutive v) per c: wave =
// 512B fully coalesced per load instr; writes 32B contiguous per lane.
// blocks 1024..1039: weights fp32 -> f16 fragment-linear (wq scaled by 8).
// -------------------------------------------------------------------------
__global__ __launch_bounds__(256, 4)
void prep_kernel(const float* __restrict__ x,
                 const float* __restrict__ wq,
                 const float* __restrict__ wk,
                 const float* __restrict__ wv,
                 const float* __restrict__ wp,
                 f16* __restrict__ xe,
                 f16* __restrict__ wq16, f16* __restrict__ wk16,
                 f16* __restrict__ wv16, f16* __restrict__ wp16)
{
    const int bid = blockIdx.x;
    const int tid = threadIdx.x;

    if (bid < NN * TT) {
        const int n = bid >> 7;
        const int t = bid & 127;
        const int v0   = (tid & 63) * 2;   // 2 consecutive v per lane
        const int csub = tid >> 6;         // 0..3 (8-col sub-block)
        f16* dstbase = xe + (size_t)(n * TT + t) * VV * 256;

        #pragma unroll
        for (int ct = 0; ct < 8; ++ct) {
            const int c0 = ct * 32 + csub * 8;
            union { int4 u[2]; f16 h[16]; } pk;
            #pragma unroll
            for (int q = 0; q < 8; ++q) {
                const float2 xv = *(const float2*)(x + (((size_t)(n * CIN + c0 + q) * TT + t) * VV) + v0);
                pk.h[q]     = (f16)xv.x;
                pk.h[8 + q] = (f16)xv.y;
            }
            f16* dst = dstbase + fragoff(v0, c0, 256);
            *(int4*)dst       = pk.u[0];
            *(int4*)(dst + 8) = pk.u[1];
        }
    } else {
        const int gid = (bid - NN * TT) * 256 + tid;   // 0..4095
        for (int i = gid; i < 163840; i += 4096) {
            const int e = i * 4;
            union { uint2 u; f16 h[4]; } pk;
            if (e < 131072) {
                const float4 v = *(const float4*)(wq + e);
                pk.h[0] = (f16)(v.x * 8.0f); pk.h[1] = (f16)(v.y * 8.0f);
                pk.h[2] = (f16)(v.z * 8.0f); pk.h[3] = (f16)(v.w * 8.0f);
                *(uint2*)(wq16 + fragoff(e >> 8, e & 255, 256)) = pk.u;
            } else if (e < 262144) {
                const int e2 = e - 131072;
                const float4 v = *(const float4*)(wk + e2);
                pk.h[0] = (f16)v.x; pk.h[1] = (f16)v.y; pk.h[2] = (f16)v.z; pk.h[3] = (f16)v.w;
                *(uint2*)(wk16 + fragoff(e2 >> 8, e2 & 255, 256)) = pk.u;
            } else if (e < 393216) {
                const int e2 = e - 262144;
                const float4 v = *(const float4*)(wv + e2);
                pk.h[0] = (f16)v.x; pk.h[1] = (f16)v.y; pk.h[2] = (f16)v.z; pk.h[3] = (f16)v.w;
                *(uint2*)(wv16 + fragoff(e2 >> 8, e2 & 255, 256)) = pk.u;
            } else {
                const int e2 = e - 393216;
                const float4 v = *(const float4*)(wp + e2);
                pk.h[0] = (f16)v.x; pk.h[1] = (f16)v.y; pk.h[2] = (f16)v.z; pk.h[3] = (f16)v.w;
                *(uint2*)(wp16 + fragoff(e2 >> 9, e2 & 511, 512)) = pk.u;
            }
        }
    }
}

// -------------------------------------------------------------------------
// In-register fragment regroup: MFMA C-layout (rows on g*4+i, col on r) for a
// 32-row x 16-col chunk -> A/B fragment layout (col on r, rows 8/lane on g).
// -------------------------------------------------------------------------
__device__ __forceinline__ f16x8 regroup32(f32x4 T0, f32x4 T1, int g, int r)
{
    union { unsigned u; f16 h[2]; } pa, pb, pc, pd;
    pa.h[0] = (f16)T0[0]; pa.h[1] = (f16)T0[1];
    pb.h[0] = (f16)T0[2]; pb.h[1] = (f16)T0[3];
    pc.h[0] = (f16)T1[0]; pc.h[1] = (f16)T1[1];
    pd.h[0] = (f16)T1[2]; pd.h[1] = (f16)T1[3];
    const int s0 = r + ((g & 1) << 5);
    const int s1 = s0 + 16;
    const bool lo = (g < 2);
    const unsigned a0 = (unsigned)__shfl((int)pa.u, s0, 64);
    const unsigned c0 = (unsigned)__shfl((int)pc.u, s0, 64);
    const unsigned b0 = (unsigned)__shfl((int)pb.u, s0, 64);
    const unsigned d0 = (unsigned)__shfl((int)pd.u, s0, 64);
    const unsigned a1 = (unsigned)__shfl((int)pa.u, s1, 64);
    const unsigned c1 = (unsigned)__shfl((int)pc.u, s1, 64);
    const unsigned b1 = (unsigned)__shfl((int)pb.u, s1, 64);
    const unsigned d1 = (unsigned)__shfl((int)pd.u, s1, 64);
    union { unsigned u[4]; f16x8 v; } out;
    out.u[0] = lo ? a0 : c0;
    out.u[1] = lo ? b0 : d0;
    out.u[2] = lo ? a1 : c1;
    out.u[3] = lo ? b1 : d1;
    return out.v;
}

// -------------------------------------------------------------------------
// Kernel B: EXACT round-5 structure (verified 194us): one block per (n,t,h),
// XCD-chunked swizzle, fragment-linear loads, TWO-PASS projection (q+k then
// v; keeps compiler at 64 VGPR without spill — merged variant spilled 2.4GB
// scratch in R6). Q in registers; K,V in LDS; ONE barrier.
// -------------------------------------------------------------------------
__global__ __launch_bounds__(256, 4)
void qkv_attn_kernel(const f16* __restrict__ xe,
                     const f16* __restrict__ wq16,
                     const f16* __restrict__ wk16,
                     const f16* __restrict__ wv16,
                     f16* __restrict__ oe)
{
    // sK: (v,128 x 72) | sVT: (d,64 x 136)
    __shared__ f16 smem[17920];
    f16* sK  = smem;              // 9216 halves
    f16* sVT = smem + 9216;       // 8704 halves

    const int tid = threadIdx.x;
    const int wid = tid >> 6;
    const int l   = tid & 63;
    const int r   = l & 15;
    const int g   = l >> 4;

    // XCD-chunked decode (grid 8192 = 8 XCD x 1024, bijective).
    const int i   = blockIdx.x;
    const int xcd = i & 7;
    const int m   = i >> 3;                 // 0..1023
    const int nt  = xcd * 128 + (m >> 3);   // 0..1023
    const int h   = m & 7;
    const int n   = nt >> 7;
    const int t   = nt & 127;

    const f16* xrow = xe + (size_t)(n * TT + t) * VV * 256;   // fragment-linear

    // ---------------- Phase 1a: q,k projection ----------------
    f32x4 accq[4][2], acck[4][2];
    #pragma unroll
    for (int dt = 0; dt < 4; ++dt)
        #pragma unroll
        for (int vt = 0; vt < 2; ++vt) { accq[dt][vt] = (f32x4)0.0f; acck[dt][vt] = (f32x4)0.0f; }

    for (int ks = 0; ks < 8; ++ks) {
        f16x8 aq[4], ak[4], bx[2];
        #pragma unroll
        for (int dt = 0; dt < 4; ++dt) {
            aq[dt] = *(const f16x8*)(wq16 + (size_t)(h * 4 + dt) * 4096 + ks * 512 + l * 8);
            ak[dt] = *(const f16x8*)(wk16 + (size_t)(h * 4 + dt) * 4096 + ks * 512 + l * 8);
        }
        #pragma unroll
        for (int vt = 0; vt < 2; ++vt)
            bx[vt] = *(const f16x8*)(xrow + (size_t)(wid * 2 + vt) * 4096 + ks * 512 + l * 8);
        #pragma unroll
        for (int dt = 0; dt < 4; ++dt)
            #pragma unroll
            for (int vt = 0; vt < 2; ++vt) {
                accq[dt][vt] = MFMA16(aq[dt], bx[vt], accq[dt][vt]);
                acck[dt][vt] = MFMA16(ak[dt], bx[vt], acck[dt][vt]);
            }
    }
    // write K transposed to (v, d) — packed b64
    #pragma unroll
    for (int dt = 0; dt < 4; ++dt)
        #pragma unroll
        for (int vt = 0; vt < 2; ++vt) {
            const int v = wid * 32 + vt * 16 + r;
            union { uint2 u; f16 h4[4]; } pk;
            #pragma unroll
            for (int i2 = 0; i2 < 4; ++i2)
                pk.h4[i2] = (f16)acck[dt][vt][i2];
            *(uint2*)&sK[v * 72 + dt * 16 + g * 4] = pk.u;
        }
    // Q stays in registers: regroup acc layout -> B-frag layout (wave-local v)
    f16x8 qfrag[2][2];   // [vt][ks]: Q[v=wid*32+vt*16+r][d=ks*32+g*8 ..+7]
    #pragma unroll
    for (int vt = 0; vt < 2; ++vt) {
        qfrag[vt][0] = regroup32(accq[0][vt], accq[1][vt], g, r);
        qfrag[vt][1] = regroup32(accq[2][vt], accq[3][vt], g, r);
    }

    // ---------------- Phase 1b: v projection ----------------
    f32x4 accv[4][2];
    #pragma unroll
    for (int dt = 0; dt < 4; ++dt)
        #pragma unroll
        for (int wt = 0; wt < 2; ++wt) accv[dt][wt] = (f32x4)0.0f;

    for (int ks = 0; ks < 8; ++ks) {
        f16x8 av[4], bx[2];
        #pragma unroll
        for (int dt = 0; dt < 4; ++dt)
            av[dt] = *(const f16x8*)(wv16 + (size_t)(h * 4 + dt) * 4096 + ks * 512 + l * 8);
        #pragma unroll
        for (int wt = 0; wt < 2; ++wt)
            bx[wt] = *(const f16x8*)(xrow + (size_t)(wid * 2 + wt) * 4096 + ks * 512 + l * 8);
        #pragma unroll
        for (int dt = 0; dt < 4; ++dt)
            #pragma unroll
            for (int wt = 0; wt < 2; ++wt)
                accv[dt][wt] = MFMA16(av[dt], bx[wt], accv[dt][wt]);
    }
    // write V^T (d, w) — column scatter b16
    #pragma unroll
    for (int dt = 0; dt < 4; ++dt)
        #pragma unroll
        for (int wt = 0; wt < 2; ++wt) {
            const int w = wid * 32 + wt * 16 + r;
            #pragma unroll
            for (int i2 = 0; i2 < 4; ++i2)
                sVT[(dt * 16 + g * 4 + i2) * 136 + w] = (f16)accv[dt][wt][i2];
        }
    __syncthreads();   // the ONLY barrier: sK/sVT complete before reads

    // ---------------- Phase 2: S^T = K Q^T (w x v), scale folded in wq ----
    f32x4 sT[8][2];
    #pragma unroll
    for (int mt = 0; mt < 8; ++mt)
        #pragma unroll
        for (int vt = 0; vt < 2; ++vt) sT[mt][vt] = (f32x4)0.0f;

    #pragma unroll
    for (int ks = 0; ks < 2; ++ks) {
        const int ko = ks * 32 + g * 8;
        #pragma unroll
        for (int mt = 0; mt < 8; ++mt) {
            const f16x8 a = *(const f16x8*)&sK[(mt * 16 + r) * 72 + ko];
            #pragma unroll
            for (int vt = 0; vt < 2; ++vt)
                sT[mt][vt] = MFMA16(a, qfrag[vt][ks], sT[mt][vt]);
        }
    }

    // ---------------- Phase 3: softmax over w (in-register) ----------------
    float inv[2];
    #pragma unroll
    for (int vt = 0; vt < 2; ++vt) {
        float mx = -3.0e38f;
        #pragma unroll
        for (int mt = 0; mt < 8; ++mt)
            #pragma unroll
            for (int i2 = 0; i2 < 4; ++i2) mx = fmaxf(mx, sT[mt][vt][i2]);
        mx = fmaxf(mx, __shfl_xor(mx, 16));
        mx = fmaxf(mx, __shfl_xor(mx, 32));
        float sm = 0.0f;
        #pragma unroll
        for (int mt = 0; mt < 8; ++mt)
            #pragma unroll
            for (int i2 = 0; i2 < 4; ++i2) {
                const float e = __expf(sT[mt][vt][i2] - mx);
                sT[mt][vt][i2] = e;
                sm += e;
            }
        sm += __shfl_xor(sm, 16);
        sm += __shfl_xor(sm, 32);
        inv[vt] = 1.0f / sm;
    }

    // ---------------- Phase 4: o^T = V^T P^T (d x v), P regrouped in-reg ----
    f32x4 oT[4][2];
    #pragma unroll
    for (int dt = 0; dt < 4; ++dt)
        #pragma unroll
        for (int vt = 0; vt < 2; ++vt) oT[dt][vt] = (f32x4)0.0f;

    #pragma unroll
    for (int ks = 0; ks < 4; ++ks) {
        const int ko = ks * 32 + g * 8;
        f16x8 pf[2];
        #pragma unroll
        for (int vt = 0; vt < 2; ++vt)
            pf[vt] = regroup32(sT[2 * ks][vt], sT[2 * ks + 1][vt], g, r);
        #pragma unroll
        for (int dt = 0; dt < 4; ++dt) {
            const f16x8 a = *(const f16x8*)&sVT[(dt * 16 + r) * 136 + ko];
            #pragma unroll
            for (int vt = 0; vt < 2; ++vt)
                oT[dt][vt] = MFMA16(a, pf[vt], oT[dt][vt]);
        }
    }

    // epilogue: normalize, store fragment-linear oe (NC=512).
    f16* oerow = oe + (size_t)(n * TT + t) * VV * 512;
    #pragma unroll
    for (int dt = 0; dt < 4; ++dt)
        #pragma unroll
        for (int vt = 0; vt < 2; ++vt) {
            union { uint2 u; f16 h4[4]; } pk;
            #pragma unroll
            for (int i2 = 0; i2 < 4; ++i2) pk.h4[i2] = (f16)(oT[dt][vt][i2] * inv[vt]);
            f16* dst = oerow + (size_t)(wid * 2 + vt) * 8192
                     + (h * 2 + (dt >> 1)) * 512
                     + ((dt & 1) * 2 + (g >> 1)) * 128
                     + r * 8 + (g & 1) * 4;
            *(uint2*)dst = pk.u;
        }
}

// -------------------------------------------------------------------------
// Kernel C: out[n,o,t,v] = wp @ o + bp. One block per (n, t, og): 256 o-rows
// x 128 v, acc[4][8]. OPERANDS SWAPPED vs R5: MFMA16(oe_frag, wp_frag, acc)
// puts v on (g*4+i) and o on r -> each lane's f32x4 = 4 consecutive v ->
// single float4 store per acc (4x fewer store instrs), bias = one scalar/lane.
// Fragment-linear loads; XCD-chunked swizzle.
// -------------------------------------------------------------------------
__global__ __launch_bounds__(256, 2)
void out_proj_kernel(const f16* __restrict__ oe,
                     const f16* __restrict__ wp16,
                     const float* __restrict__ bp,
                     float* __restrict__ out)
{
    const int tid = threadIdx.x;
    const int wid = tid >> 6;
    const int l   = tid & 63;
    const int r   = l & 15;
    const int g   = l >> 4;

    // grid = 2048 = 8 XCDs x 256.
    const int i   = blockIdx.x;
    const int xcd = i & 7;
    const int m   = i >> 3;                 // 0..255
    const int nt  = xcd * 128 + (m >> 1);   // 0..1023
    const int og  = m & 1;
    const int n   = nt >> 7;
    const int t   = nt & 127;

    const f16* brow = oe + (size_t)(n * TT + t) * VV * 512;   // fragment-linear

    f32x4 acc[4][8];
    #pragma unroll
    for (int mi = 0; mi < 4; ++mi)
        #pragma unroll
        for (int nt2 = 0; nt2 < 8; ++nt2) acc[mi][nt2] = (f32x4)0.0f;

    for (int ks = 0; ks < 16; ++ks) {
        f16x8 a[4], b[8];
        #pragma unroll
        for (int mi = 0; mi < 4; ++mi)
            a[mi] = *(const f16x8*)(wp16 + (size_t)(og * 16 + wid * 4 + mi) * 8192 + ks * 512 + l * 8);
        #pragma unroll
        for (int nt2 = 0; nt2 < 8; ++nt2)
            b[nt2] = *(const f16x8*)(brow + (size_t)nt2 * 8192 + ks * 512 + l * 8);
        #pragma unroll
        for (int mi = 0; mi < 4; ++mi)
            #pragma unroll
            for (int nt2 = 0; nt2 < 8; ++nt2)
                acc[mi][nt2] = MFMA16(b[nt2], a[mi], acc[mi][nt2]);   // swapped: v on rows
    }

    #pragma unroll
    for (int mi = 0; mi < 4; ++mi) {
        const int o = og * 256 + (wid * 4 + mi) * 16 + r;
        const float bv = bp[o];
        float* orow = out + ((size_t)(n * OUTC + o) * TT + t) * VV;
        #pragma unroll
        for (int nt2 = 0; nt2 < 8; ++nt2) {
            const int v = nt2 * 16 + g * 4;
            float4 f;
            f.x = acc[mi][nt2][0] + bv;
            f.y = acc[mi][nt2][1] + bv;
            f.z = acc[mi][nt2][2] + bv;
            f.w = acc[mi][nt2][3] + bv;
            *(float4*)(orow + v) = f;
        }
    }
}

extern "C" void kernel_launch(void* const* d_in, const int* in_sizes, int n_in,
                              void* d_out, int out_size, void* d_ws, size_t ws_size,
                              hipStream_t stream)
{
    const float* x  = (const float*)d_in[0];
    const float* wq = (const float*)d_in[1];
    const float* wk = (const float*)d_in[2];
    const float* wv = (const float*)d_in[3];
    const float* wp = (const float*)d_in[4];
    const float* bp = (const float*)d_in[5];
    float* out = (float*)d_out;

    char* ws = (char*)d_ws;
    f16* xe   = (f16*)(ws + XE_OFF);
    f16* wq16 = (f16*)(ws + WQ_OFF);
    f16* wk16 = (f16*)(ws + WK_OFF);
    f16* wv16 = (f16*)(ws + WV_OFF);
    f16* wp16 = (f16*)(ws + WP_OFF);
    f16* oe   = (f16*)(ws + OE_OFF);

    prep_kernel<<<NN * TT + 16, 256, 0, stream>>>(x, wq, wk, wv, wp, xe, wq16, wk16, wv16, wp16);
    qkv_attn_kernel<<<NN * TT * HH, 256, 0, stream>>>(xe, wq16, wk16, wv16, oe);
    out_proj_kernel<<<NN * TT * 2, 256, 0, stream>>>(oe, wp16, bp, out);
}